// Round 1
// baseline (326.338 us; speedup 1.0000x reference)
//
#include <hip/hip_runtime.h>

#define DIM 32
#define BLOCK 256
#define RS 36   // padded LDS row stride in floats: bank-group (row+chunk)%8 is uniform

// d_ws layout: c[32][32] folded coefficients, then s[32], then m[32]  (1088 floats)
//   c[i][j] = -P[i][j]/P[i][i]  (j != i),  c[i][i] = 0
//   s[i]    = sqrt(1/P[i][i])
//   m[i]    = mu[i]
__global__ __launch_bounds__(256) void gibbs_setup_kernel(
    const float* __restrict__ prec,
    const float* __restrict__ mu,
    float* __restrict__ ws)
{
    const int t = threadIdx.x;
#pragma unroll
    for (int k = 0; k < 4; ++k) {
        const int idx = t * 4 + k;
        const int i = idx >> 5;
        const int j = idx & 31;
        const float pii = prec[i * DIM + i];
        ws[idx] = (j == i) ? 0.0f : (-prec[idx] / pii);
    }
    if (t < DIM) {
        const float pii = prec[t * DIM + t];
        ws[1024 + t] = sqrtf(1.0f / pii);
        ws[1056 + t] = mu[t];
    }
}

// Same association as the previous (passing) kernel: 4 chains of 8 FMAs.
#define G8(C, X, o) \
    ((C)[(o)+0]*(X)[(o)+0] + (C)[(o)+1]*(X)[(o)+1] + (C)[(o)+2]*(X)[(o)+2] + (C)[(o)+3]*(X)[(o)+3] \
   + (C)[(o)+4]*(X)[(o)+4] + (C)[(o)+5]*(X)[(o)+5] + (C)[(o)+6]*(X)[(o)+6] + (C)[(o)+7]*(X)[(o)+7])

// One thread = one row, but all global I/O is wave-coalesced through a padded
// per-wave LDS chunk (64 rows x 36 floats = 9 KB). No cross-wave sharing ->
// no __syncthreads at all; only intra-wave lgkmcnt ordering.
__global__ __launch_bounds__(BLOCK, 4) void gibbs_sweep_kernel(
    const float* __restrict__ x,
    const float* __restrict__ noise,
    const float* __restrict__ ws,
    float* __restrict__ out)
{
    __shared__ float lds[4][64 * RS];   // 4 waves * 9216 B = 36 KB/block

    const float* __restrict__ cw = ws;          // 32x32 folded coefficients
    const float* __restrict__ sw = ws + 1024;   // sqrt(1/Pii)
    const float* __restrict__ mw = ws + 1056;   // mu

    const int wid  = threadIdx.x >> 6;
    const int lane = threadIdx.x & 63;
    const long rowbase = (long)blockIdx.x * BLOCK + wid * 64;  // wave's first row

    const float4* __restrict__ gx = (const float4*)(x     + rowbase * DIM);
    const float4* __restrict__ gn = (const float4*)(noise + rowbase * DIM);
    float4* __restrict__ go = (float4*)(out + rowbase * DIM);

    float* L = lds[wid];

    // Issue ALL global loads first (perfectly coalesced: lane l -> float4 k*64+l,
    // 1 KB per instruction over the wave's contiguous 8 KB row span).
    float4 vx[8], vn[8];
#pragma unroll
    for (int k = 0; k < 8; ++k) vx[k] = gx[k * 64 + lane];
#pragma unroll
    for (int k = 0; k < 8; ++k) vn[k] = gn[k * 64 + lane];

    float xv[32], nv[32];

    // x: regs -> padded LDS -> row-in-registers.
    // write: float4 f covers (row f>>3, chunk f&7); bank-group (row+chunk)%8 uniform.
#pragma unroll
    for (int k = 0; k < 8; ++k) {
        const int f = k * 64 + lane;
        *(float4*)(L + (f >> 3) * RS + (f & 7) * 4) = vx[k];
    }
#pragma unroll
    for (int c = 0; c < 8; ++c) {
        const float4 v = *(const float4*)(L + lane * RS + c * 4);
        xv[c * 4 + 0] = v.x; xv[c * 4 + 1] = v.y;
        xv[c * 4 + 2] = v.z; xv[c * 4 + 3] = v.w;
    }

    // noise through the same chunk (intra-wave DS ordering keeps this safe).
#pragma unroll
    for (int k = 0; k < 8; ++k) {
        const int f = k * 64 + lane;
        *(float4*)(L + (f >> 3) * RS + (f & 7) * 4) = vn[k];
    }
#pragma unroll
    for (int c = 0; c < 8; ++c) {
        const float4 v = *(const float4*)(L + lane * RS + c * 4);
        nv[c * 4 + 0] = v.x; nv[c * 4 + 1] = v.y;
        nv[c * 4 + 2] = v.z; nv[c * 4 + 3] = v.w;
    }

    // Sequential Gibbs sweep; coefficients are wave-uniform -> scalar loads.
    // Numeric grouping identical to the previous passing kernel.
#pragma unroll
    for (int i = 0; i < 32; ++i) {
        const float* __restrict__ ci = cw + i * DIM;
        const float d = ((G8(ci, xv, 0) + G8(ci, xv, 8))
                       + (G8(ci, xv, 16) + G8(ci, xv, 24)));
        xv[i] = fmaf(sw[i], nv[i], mw[i] + d);
    }

    // out: registers -> padded LDS -> coalesced global stores.
#pragma unroll
    for (int c = 0; c < 8; ++c) {
        *(float4*)(L + lane * RS + c * 4) =
            make_float4(xv[c * 4 + 0], xv[c * 4 + 1], xv[c * 4 + 2], xv[c * 4 + 3]);
    }
#pragma unroll
    for (int k = 0; k < 8; ++k) {
        const int f = k * 64 + lane;
        go[f] = *(const float4*)(L + (f >> 3) * RS + (f & 7) * 4);
    }
}

extern "C" void kernel_launch(void* const* d_in, const int* in_sizes, int n_in,
                              void* d_out, int out_size, void* d_ws, size_t ws_size,
                              hipStream_t stream) {
    const float* x     = (const float*)d_in[0];  // (B, 32)
    const float* noise = (const float*)d_in[1];  // (B, 32)
    const float* prec  = (const float*)d_in[2];  // (32, 32)
    const float* mu    = (const float*)d_in[3];  // (32,)
    float* out = (float*)d_out;
    float* ws  = (float*)d_ws;                   // needs 1088 floats (4.25 KB)

    const int B = in_sizes[0] / DIM;             // 1048576
    const int grid = B / BLOCK;                  // 4096 blocks

    gibbs_setup_kernel<<<1, 256, 0, stream>>>(prec, mu, ws);
    gibbs_sweep_kernel<<<grid, BLOCK, 0, stream>>>(x, noise, ws, out);
}